// Round 1
// baseline (61.731 us; speedup 1.0000x reference)
//
#include <hip/hip_runtime.h>

// TemporalNorm: causal rolling-window (W=128) mean/var norm over time, per (b,d).
// x: [B,T,D] f32, weight/bias: [D] f32, out: [B,T,D] f32.
constexpr int Bb  = 32;
constexpr int Tt  = 4096;
constexpr int Dd  = 256;
constexpr int Ww  = 128;
constexpr float EPSF = 1e-5f;

constexpr int CT  = 128;          // time chunk per block
constexpr int NC  = Tt / CT;      // 32 chunks
constexpr int NWG = Bb * NC;      // 1024 blocks

__global__ __launch_bounds__(256, 4)
void TemporalNorm_kernel(const float* __restrict__ x,
                         const float* __restrict__ wgt,
                         const float* __restrict__ bia,
                         float* __restrict__ out) {
    // XCD-contiguous swizzle: launch index i -> logical block lb such that each
    // XCD (i%8 round-robin) owns a contiguous range of (b, chunk) pairs.
    // NWG % 8 == 0 -> bijective.
    const int i  = blockIdx.x;
    const int lb = (i & 7) * (NWG / 8) + (i >> 3);
    const int b  = lb / NC;
    const int c  = lb % NC;
    const int d  = threadIdx.x;
    const int t0 = c * CT;

    const float* __restrict__ xb = x   + (size_t)b * Tt * Dd + d;
    float*       __restrict__ ob = out + (size_t)b * Tt * Dd + d;
    const float w  = wgt[d];
    const float bi = bia[d];

    float s1 = 0.0f, s2 = 0.0f;

    if (t0 >= Ww) {
        // ---- steady-state chunks: window is always full (n = W) ----
        // warm-up: sum over [t0-W, t0)
        for (int t = t0 - Ww; t < t0; t += 4) {
            float a0 = xb[(t + 0) * Dd];
            float a1 = xb[(t + 1) * Dd];
            float a2 = xb[(t + 2) * Dd];
            float a3 = xb[(t + 3) * Dd];
            s1 += (a0 + a1) + (a2 + a3);
            s2 += (a0 * a0 + a1 * a1) + (a2 * a2 + a3 * a3);
        }
        const float rn = 1.0f / (float)Ww;   // exact (1/128)
        for (int t = t0; t < t0 + CT; t += 4) {
            // batch 8 independent loads for ILP
            float a0 = xb[(t + 0) * Dd];
            float a1 = xb[(t + 1) * Dd];
            float a2 = xb[(t + 2) * Dd];
            float a3 = xb[(t + 3) * Dd];
            float o0 = xb[(t + 0 - Ww) * Dd];
            float o1 = xb[(t + 1 - Ww) * Dd];
            float o2 = xb[(t + 2 - Ww) * Dd];
            float o3 = xb[(t + 3 - Ww) * Dd];

            s1 += a0 - o0; s2 += a0 * a0 - o0 * o0;
            {
                float loc = s1 * rn;
                float var = s2 * rn - loc * loc;
                float inv = rsqrtf(var + EPSF);
                ob[(t + 0) * Dd] = (a0 - loc) * inv * w + bi;
            }
            s1 += a1 - o1; s2 += a1 * a1 - o1 * o1;
            {
                float loc = s1 * rn;
                float var = s2 * rn - loc * loc;
                float inv = rsqrtf(var + EPSF);
                ob[(t + 1) * Dd] = (a1 - loc) * inv * w + bi;
            }
            s1 += a2 - o2; s2 += a2 * a2 - o2 * o2;
            {
                float loc = s1 * rn;
                float var = s2 * rn - loc * loc;
                float inv = rsqrtf(var + EPSF);
                ob[(t + 2) * Dd] = (a2 - loc) * inv * w + bi;
            }
            s1 += a3 - o3; s2 += a3 * a3 - o3 * o3;
            {
                float loc = s1 * rn;
                float var = s2 * rn - loc * loc;
                float inv = rsqrtf(var + EPSF);
                ob[(t + 3) * Dd] = (a3 - loc) * inv * w + bi;
            }
        }
    } else {
        // ---- chunk 0 (t0 == 0): growing window, n = min(t+1, W) ----
        for (int t = 0; t < CT; ++t) {
            float a = xb[t * Dd];
            s1 += a; s2 += a * a;
            if (t >= Ww) {
                float o = xb[(t - Ww) * Dd];
                s1 -= o; s2 -= o * o;
            }
            float n   = (float)((t + 1 < Ww) ? (t + 1) : Ww);
            float rn  = 1.0f / n;
            float loc = s1 * rn;
            float var = s2 * rn - loc * loc;
            float inv = rsqrtf(var + EPSF);
            ob[t * Dd] = (a - loc) * inv * w + bi;
        }
    }
}

extern "C" void kernel_launch(void* const* d_in, const int* in_sizes, int n_in,
                              void* d_out, int out_size, void* d_ws, size_t ws_size,
                              hipStream_t stream) {
    const float* x   = (const float*)d_in[0];
    const float* wgt = (const float*)d_in[1];
    const float* bia = (const float*)d_in[2];
    float* out = (float*)d_out;

    hipLaunchKernelGGL(TemporalNorm_kernel, dim3(NWG), dim3(256), 0, stream,
                       x, wgt, bia, out);
}